// Round 1
// baseline (426.112 us; speedup 1.0000x reference)
//
#include <hip/hip_runtime.h>
#include <math.h>

// EdgeFocusedGraphNetwork — collapsed form.
//
// Key algebra (see journal): fe[b,i,j,:] stays rank-structured P[b,i]+Q[b,j]+r
// through every step; softmax over i cancels the j-part and const part, so
// Q, r, b_fe, b_ue, b_attn never influence the output. Per step we only need:
//   A   = fv @ W_fe[:, :H].T                  (1024,256)
//   P'  = [A | P] @ W_ue.T                    (1024,256)   (K=512 concat GEMM)
//   S   = P' @ W_attn.T                       (1024,256)
//   xh  = (fv*mask) @ W_agg.T + b_agg         (1024,256)
//   agg[b,h] = sigmoid( sum_i softmax_i(S[b,i,h]) * xh[b,i,h] )   (8,256)
//   fv' = [xh | agg-broadcast] @ W_uv.T + b_uv
// Total ~5e9 FLOPs, ~50 MB traffic — L2 resident, latency/launch bound.

#define BDIM 8
#define LDIM 128
#define MROWS (BDIM * LDIM)   // 1024
#define H 256
#define NINP 512

// Generic f32 GEMM: Y[m,n] = (sum_k X[m,k]*rowscale[m] * W[n*ldw+k]) + bias[n]
// M fixed = grid.x*32, N = grid.y*32, K runtime (multiple of 32).
// 32x32 tile, 256 threads, 2x2 micro-tile. LDS padded to stride 33 -> the
// inner-loop reads Xs[2ty][kk] (broadcast within ty-group, 4 distinct banks)
// and Ws[2tx][kk] (bank = (2tx+kk)%32, all distinct) are conflict-free.
__global__ __launch_bounds__(256) void gemm_xwt(
    const float* __restrict__ X, int ldx,
    const float* __restrict__ W, int ldw,
    const float* __restrict__ bias,
    const float* __restrict__ rowscale,
    float* __restrict__ Y, int ldy,
    int K)
{
    __shared__ float Xs[32][33];
    __shared__ float Ws[32][33];
    const int bm = blockIdx.x << 5;
    const int bn = blockIdx.y << 5;
    const int tid = threadIdx.x;
    const int lr = tid >> 3;          // 0..31 : tile row for loading
    const int lc = (tid & 7) << 2;    // 0..28 : k-offset (float4)
    const int ty = tid >> 4;          // 0..15
    const int tx = tid & 15;          // 0..15

    const float* xrow = X + (size_t)(bm + lr) * ldx + lc;
    const float* wrow = W + (size_t)(bn + lr) * ldw + lc;
    const float rsc = rowscale ? rowscale[bm + lr] : 1.0f;

    float a00 = 0.f, a01 = 0.f, a10 = 0.f, a11 = 0.f;

    for (int k0 = 0; k0 < K; k0 += 32) {
        float4 xv = *(const float4*)(xrow + k0);
        float4 wv = *(const float4*)(wrow + k0);
        xv.x *= rsc; xv.y *= rsc; xv.z *= rsc; xv.w *= rsc;
        __syncthreads();
        Xs[lr][lc + 0] = xv.x; Xs[lr][lc + 1] = xv.y;
        Xs[lr][lc + 2] = xv.z; Xs[lr][lc + 3] = xv.w;
        Ws[lr][lc + 0] = wv.x; Ws[lr][lc + 1] = wv.y;
        Ws[lr][lc + 2] = wv.z; Ws[lr][lc + 3] = wv.w;
        __syncthreads();
        #pragma unroll
        for (int kk = 0; kk < 32; ++kk) {
            float x0 = Xs[2 * ty][kk],     x1 = Xs[2 * ty + 1][kk];
            float w0 = Ws[2 * tx][kk],     w1 = Ws[2 * tx + 1][kk];
            a00 = fmaf(x0, w0, a00);
            a01 = fmaf(x0, w1, a01);
            a10 = fmaf(x1, w0, a10);
            a11 = fmaf(x1, w1, a11);
        }
    }
    const float b0 = bias ? bias[bn + 2 * tx]     : 0.f;
    const float b1 = bias ? bias[bn + 2 * tx + 1] : 0.f;
    float* y0 = Y + (size_t)(bm + 2 * ty) * ldy + bn + 2 * tx;
    float* y1 = y0 + ldy;
    y0[0] = a00 + b0; y0[1] = a01 + b1;
    y1[0] = a10 + b0; y1[1] = a11 + b1;
}

// Per (b,h): online softmax over i of S[b,i,h], weighted by xhid[b,i,h],
// sigmoid, then broadcast into XC[:, H+h] for all 128 rows of batch b.
// One block per b (8 blocks), one thread per h (256) -> fully coalesced
// column walks (stride H / 2H floats, consecutive h across lanes).
__global__ __launch_bounds__(256) void agg_softmax(
    const float* __restrict__ S,   // (B, L, H)
    float* __restrict__ XC)        // (B*L, 2H): [:, :H] = xhid (read), [:, H:] = agg (write)
{
    const int b = blockIdx.x;
    const int h = threadIdx.x;
    const float* Sp = S + (size_t)b * LDIM * H + h;
    const float* Xp = XC + (size_t)b * LDIM * (2 * H) + h;
    float m = -3.402823466e38f, s = 0.f, a = 0.f;
    for (int i = 0; i < LDIM; ++i) {
        float v = Sp[(size_t)i * H];
        float x = Xp[(size_t)i * (2 * H)];
        float nm = fmaxf(m, v);
        float sc = expf(m - nm);   // 0 on first iteration
        float e  = expf(v - nm);
        s = s * sc + e;
        a = a * sc + e * x;
        m = nm;
    }
    float g = a / s;
    g = 1.0f / (1.0f + expf(-g));
    float* Op = XC + (size_t)b * LDIM * (2 * H) + H + h;
    #pragma unroll 4
    for (int j = 0; j < LDIM; ++j) Op[(size_t)j * (2 * H)] = g;
}

extern "C" void kernel_launch(void* const* d_in, const int* in_sizes, int n_in,
                              void* d_out, int out_size, void* d_ws, size_t ws_size,
                              hipStream_t stream)
{
    const float* feat   = (const float*)d_in[0];
    const float* mask   = (const float*)d_in[1];
    const float* W_inp  = (const float*)d_in[2];
    const float* b_inp  = (const float*)d_in[3];
    const float* W_oup  = (const float*)d_in[4];
    const float* b_oup  = (const float*)d_in[5];
    const float* W_fe   = (const float*)d_in[6];
    // d_in[7] = b_fe   : cancelled by softmax shift-invariance
    const float* W_ue   = (const float*)d_in[8];
    // d_in[9] = b_ue   : cancelled
    const float* W_agg  = (const float*)d_in[10];
    const float* b_agg  = (const float*)d_in[11];
    const float* W_uv   = (const float*)d_in[12];
    const float* b_uv   = (const float*)d_in[13];
    const float* W_attn = (const float*)d_in[14];
    // d_in[15] = b_attn: cancelled
    float* out = (float*)d_out;

    // Workspace layout (floats), total 2,359,296 f32 = 9.4 MB.
    float* ws = (float*)d_ws;
    float* FVb[2];
    FVb[0] = ws;                        // fv ping (1024,256)
    FVb[1] = FVb[0] + MROWS * H;        // fv pong
    float* CA[2];
    CA[0] = FVb[1] + MROWS * H;         // [A | P] concat ping (1024,512)
    CA[1] = CA[0] + MROWS * 2 * H;      // pong
    float* XC = CA[1] + MROWS * 2 * H;  // [xhid | agg] concat (1024,512)
    float* S  = XC + MROWS * 2 * H;     // attn i-part (1024,256)

    const dim3 blk(256);
    const dim3 gh(MROWS / 32, H / 32);      // N=256 GEMMs
    const dim3 go(MROWS / 32, NINP / 32);   // N=512 output GEMM

    // fv0 = feat @ W_inp.T + b_inp
    gemm_xwt<<<gh, blk, 0, stream>>>(feat, NINP, W_inp, NINP, b_inp, nullptr,
                                     FVb[0], H, NINP);
    // P0 = fv0 @ W_fe[:, :H].T  -> CA[0][:, H:]
    gemm_xwt<<<gh, blk, 0, stream>>>(FVb[0], H, W_fe, 2 * H, nullptr, nullptr,
                                     CA[0] + H, 2 * H, H);

    int p = 0;
    for (int t = 0; t < 3; ++t) {
        const float* fin = FVb[t & 1];
        float* fout = FVb[(t + 1) & 1];
        // A = fin @ W_fe[:, :H].T -> CA[p][:, 0:H]
        gemm_xwt<<<gh, blk, 0, stream>>>(fin, H, W_fe, 2 * H, nullptr, nullptr,
                                         CA[p], 2 * H, H);
        // P' = [A | P] @ W_ue.T -> CA[1-p][:, H:]
        gemm_xwt<<<gh, blk, 0, stream>>>(CA[p], 2 * H, W_ue, 2 * H, nullptr, nullptr,
                                         CA[1 - p] + H, 2 * H, 2 * H);
        p ^= 1;
        // S = P' @ W_attn.T   (b_attn cancels in softmax)
        gemm_xwt<<<gh, blk, 0, stream>>>(CA[p] + H, 2 * H, W_attn, H, nullptr, nullptr,
                                         S, H, H);
        // xhid = (fin * mask) @ W_agg.T + b_agg -> XC[:, 0:H]
        gemm_xwt<<<gh, blk, 0, stream>>>(fin, H, W_agg, H, b_agg, mask,
                                         XC, 2 * H, H);
        // agg[b,h] (j-independent!) -> broadcast into XC[:, H:]
        agg_softmax<<<dim3(BDIM), blk, 0, stream>>>(S, XC);
        // fv' = [xhid | agg] @ W_uv.T + b_uv
        gemm_xwt<<<gh, blk, 0, stream>>>(XC, 2 * H, W_uv, 2 * H, b_uv, nullptr,
                                         fout, H, 2 * H);
    }
    // out = fv3 @ W_oup.T + b_oup   (fv3 lives in FVb[1])
    gemm_xwt<<<go, blk, 0, stream>>>(FVb[1], H, W_oup, H, b_oup, nullptr,
                                     out, NINP, H);
}